// Round 4
// baseline (2154.913 us; speedup 1.0000x reference)
//
#include <hip/hip_runtime.h>
#include <stdint.h>

// ---------------- problem constants ----------------
#define N_E   8192
#define EDIM  256
#define NB    16
#define HH    32
#define WW    32
#define HW    1024            // H*W
#define NI    16384           // NB*HW (rows of zf)
#define NELEM 4194304         // NB*EDIM*HW

#define MARGIN    2.5e-4f     // z-path candidate margin vs bf16-mfma error (~40 sigma)
#define MARGIN_D1 2e-8f       // d1-path margin (~100 sigma of bf16 dot error)

// output flat offsets (reference return order)
#define O_ZQ   0
#define O_LOSS 4194304
#define O_DIST 4194305
#define O_IDX  4194817
#define O_ZFL  4211201
#define O_CBV  8405505
#define O_TMD  8405506

// workspace byte offsets (~20 MB total)
#define WS_PMIN  0            // u64  * 16384
#define WS_IDX   131072       // i32  * 16384
#define WS_DMIN  196608       // f32  * 16384
#define WS_E2    262144       // f32  * 8192
#define WS_Z2    294912       // f32  * 16384
#define WS_MSE   360448       // double
#define WS_MIND  360512       // f32  * 8192
#define WS_ZA    1048576      // bf16 * 16384*256 fragment-major (8 MB)
#define WS_EB    9437184      // bf16 * 8192*256 fragment-major (4 MB)
#define WS_M128  13631488     // f32  * 16384*64 (4 MB) per-(row,128col-group) min
#define WS_MD1   17825792     // f32  * 8192*64  (2 MB)

typedef __attribute__((ext_vector_type(8))) short bf16x8;
typedef __attribute__((ext_vector_type(4))) float f32x4;

__device__ __forceinline__ short f2bf(float f) {   // round-to-nearest-even
    unsigned u = __float_as_uint(f);
    u += 0x7fffu + ((u >> 16) & 1u);
    return (short)(u >> 16);
}

// ---------------- init (ws is poisoned 0xAA every launch) ----------------
__global__ void k_init(double* __restrict__ mse) {
    if (threadIdx.x == 0) *mse = 0.0;
}

// ---------------- e2[n] = sum_c emb[n,c]^2 ----------------
__global__ void k_e2(const float* __restrict__ emb, float* __restrict__ e2) {
    int row  = blockIdx.x * 4 + (threadIdx.x >> 6);
    int lane = threadIdx.x & 63;
    float4 v = *reinterpret_cast<const float4*>(emb + (size_t)row * EDIM + lane * 4);
    float s = v.x * v.x + v.y * v.y + v.z * v.z + v.w * v.w;
    #pragma unroll
    for (int m = 32; m; m >>= 1) s += __shfl_xor(s, m);
    if (lane == 0) e2[row] = s;
}

// ---------------- z2[i] = sum_c z[b,c,h,w]^2  (i = b*1024+hw) ----------------
__global__ void k_z2(const float* __restrict__ z, float* __restrict__ z2) {
    int i = blockIdx.x * 256 + threadIdx.x;
    int b = i >> 10, hw = i & 1023;
    const float* p = z + (size_t)b * EDIM * HW + hw;
    float s = 0.f;
    #pragma unroll 8
    for (int c = 0; c < EDIM; ++c) { float v = p[(size_t)c * HW]; s += v * v; }
    z2[i] = s;
}

// ---------------- z (b,c,hw) -> zA bf16 fragment-major ----------------
// zA[(ig*32 + kq)*16 + r] = bf16x8 of z row i=ig*16+r, c=kq*8..+7
// A-frag for 16x16x32: lane l holds row=l&15, k=(l>>4)*8+j
__global__ void k_convert_z(const float* __restrict__ z, bf16x8* __restrict__ zA) {
    __shared__ float lds[64][65];
    const int t   = threadIdx.x;
    const int hw0 = blockIdx.x * 64;
    const int c0  = blockIdx.y * 64;
    const int b   = blockIdx.z;
    #pragma unroll
    for (int cc = 0; cc < 4; ++cc) {
        const int cl = cc * 16 + (t >> 4);
        const float4 v = *reinterpret_cast<const float4*>(
            z + ((size_t)(b * 256 + c0 + cl) << 10) + hw0 + (t & 15) * 4);
        lds[cl][(t & 15) * 4 + 0] = v.x; lds[cl][(t & 15) * 4 + 1] = v.y;
        lds[cl][(t & 15) * 4 + 2] = v.z; lds[cl][(t & 15) * 4 + 3] = v.w;
    }
    __syncthreads();
    const int hl = t & 63;
    const int i  = b * 1024 + hw0 + hl;
    const int ig = i >> 4, r = i & 15;
    #pragma unroll
    for (int half = 0; half < 2; ++half) {
        const int kqi = (t >> 6) + half * 4;          // 0..7 local kq
        const int kq  = (c0 >> 3) + kqi;
        bf16x8 o;
        #pragma unroll
        for (int j = 0; j < 8; ++j) o[j] = f2bf(lds[kqi * 8 + j][hl]);
        zA[(ig * 32 + kq) * 16 + r] = o;
    }
}

// ---------------- emb (n,c) -> eB bf16 fragment-major ----------------
// eB[(g*32 + kq)*16 + c16] = bf16x8 of emb row n=g*16+c16, c=kq*8..+7
__global__ void k_convert_e(const float* __restrict__ emb, bf16x8* __restrict__ eB) {
    const int t  = threadIdx.x;
    const int kq = t & 31;
    const int n  = blockIdx.x * 8 + (t >> 5);
    const float4 u = *reinterpret_cast<const float4*>(emb + (size_t)n * EDIM + kq * 8);
    const float4 v = *reinterpret_cast<const float4*>(emb + (size_t)n * EDIM + kq * 8 + 4);
    bf16x8 o;
    o[0] = f2bf(u.x); o[1] = f2bf(u.y); o[2] = f2bf(u.z); o[3] = f2bf(u.w);
    o[4] = f2bf(v.x); o[5] = f2bf(v.y); o[6] = f2bf(v.z); o[7] = f2bf(v.w);
    eB[((n >> 4) * 32 + kq) * 16 + (n & 15)] = o;
}

// ---------------- MFMA candidate pass (z path) ----------------
// S[i,n] = dot(z_i, e_n) via bf16 MFMA; per-(row, 128-col group) min of
// (e2[n] - 2 S) -> m128[row][64]. z2 is row-constant: drops out of argmin.
__launch_bounds__(256, 2)
__global__ void k_cand(const bf16x8* __restrict__ zA, const bf16x8* __restrict__ eB,
                       const float* __restrict__ e2, float* __restrict__ m128) {
    const int t = threadIdx.x;
    const int w = t >> 6, l = t & 63;
    const int lo16 = l & 15, hi4 = l >> 4;
    const int iblk = blockIdx.x, chunk = blockIdx.y;
    const int ig0 = (iblk * 128 + w * 32) >> 4;

    bf16x8 a[2][8];
    #pragma unroll
    for (int ig = 0; ig < 2; ++ig)
        #pragma unroll
        for (int st = 0; st < 8; ++st)
            a[ig][st] = zA[((ig0 + ig) * 32 + st * 4 + hi4) * 16 + lo16];

    for (int ns = 0; ns < 8; ++ns) {
        const int n0 = chunk * 1024 + ns * 128;
        f32x4 acc[2][8];
        #pragma unroll
        for (int ig = 0; ig < 2; ++ig)
            #pragma unroll
            for (int cg = 0; cg < 8; ++cg) acc[ig][cg] = (f32x4){0.f, 0.f, 0.f, 0.f};
        float e2v[8];
        #pragma unroll
        for (int cg = 0; cg < 8; ++cg) e2v[cg] = e2[n0 + cg * 16 + lo16];

        #pragma unroll
        for (int st = 0; st < 8; ++st) {
            #pragma unroll
            for (int cg = 0; cg < 8; ++cg) {
                const bf16x8 b = eB[(((n0 >> 4) + cg) * 32 + st * 4 + hi4) * 16 + lo16];
                acc[0][cg] = __builtin_amdgcn_mfma_f32_16x16x32_bf16(a[0][st], b, acc[0][cg], 0, 0, 0);
                acc[1][cg] = __builtin_amdgcn_mfma_f32_16x16x32_bf16(a[1][st], b, acc[1][cg], 0, 0, 0);
            }
        }
        // C/D layout: col=lane&15, row=(lane>>4)*4+reg  [m89-verified]
        // min over all 128 cols of this ns-step -> one value per row
        #pragma unroll
        for (int ig = 0; ig < 2; ++ig) {
            #pragma unroll
            for (int reg = 0; reg < 4; ++reg) {
                float v = fmaf(-2.f, acc[ig][0][reg], e2v[0]);
                #pragma unroll
                for (int cg = 1; cg < 8; ++cg)
                    v = fminf(v, fmaf(-2.f, acc[ig][cg][reg], e2v[cg]));
                v = fminf(v, __shfl_xor(v, 1));
                v = fminf(v, __shfl_xor(v, 2));
                v = fminf(v, __shfl_xor(v, 4));
                v = fminf(v, __shfl_xor(v, 8));
                if (lo16 == ns) {
                    const int row = iblk * 128 + w * 32 + ig * 16 + hi4 * 4 + reg;
                    m128[row * 64 + chunk * 8 + ns] = v;
                }
            }
        }
    }
}

// ---------------- MFMA candidate pass (d1 path): both operands = eB ----------
__launch_bounds__(256, 2)
__global__ void k_cand_d1(const bf16x8* __restrict__ eB, const float* __restrict__ e2,
                          float* __restrict__ md1) {
    const int t = threadIdx.x;
    const int w = t >> 6, l = t & 63;
    const int lo16 = l & 15, hi4 = l >> 4;
    const int iblk = blockIdx.x, chunk = blockIdx.y;
    const int ig0 = (iblk * 128 + w * 32) >> 4;

    bf16x8 a[2][8];
    #pragma unroll
    for (int ig = 0; ig < 2; ++ig)
        #pragma unroll
        for (int st = 0; st < 8; ++st)
            a[ig][st] = eB[((ig0 + ig) * 32 + st * 4 + hi4) * 16 + lo16];

    for (int ns = 0; ns < 8; ++ns) {
        const int n0 = chunk * 1024 + ns * 128;   // m-range
        f32x4 acc[2][8];
        #pragma unroll
        for (int ig = 0; ig < 2; ++ig)
            #pragma unroll
            for (int cg = 0; cg < 8; ++cg) acc[ig][cg] = (f32x4){0.f, 0.f, 0.f, 0.f};
        float e2v[8];
        #pragma unroll
        for (int cg = 0; cg < 8; ++cg) e2v[cg] = e2[n0 + cg * 16 + lo16];

        #pragma unroll
        for (int st = 0; st < 8; ++st) {
            #pragma unroll
            for (int cg = 0; cg < 8; ++cg) {
                const bf16x8 b = eB[(((n0 >> 4) + cg) * 32 + st * 4 + hi4) * 16 + lo16];
                acc[0][cg] = __builtin_amdgcn_mfma_f32_16x16x32_bf16(a[0][st], b, acc[0][cg], 0, 0, 0);
                acc[1][cg] = __builtin_amdgcn_mfma_f32_16x16x32_bf16(a[1][st], b, acc[1][cg], 0, 0, 0);
            }
        }
        #pragma unroll
        for (int ig = 0; ig < 2; ++ig) {
            #pragma unroll
            for (int reg = 0; reg < 4; ++reg) {
                float v = fmaf(-2.f, acc[ig][0][reg], e2v[0]);
                #pragma unroll
                for (int cg = 1; cg < 8; ++cg)
                    v = fminf(v, fmaf(-2.f, acc[ig][cg][reg], e2v[cg]));
                v = fminf(v, __shfl_xor(v, 1));
                v = fminf(v, __shfl_xor(v, 2));
                v = fminf(v, __shfl_xor(v, 4));
                v = fminf(v, __shfl_xor(v, 8));
                if (lo16 == ns) {
                    const int row = iblk * 128 + w * 32 + ig * 16 + hi4 * 4 + reg; // = n
                    md1[row * 64 + chunk * 8 + ns] = v;
                }
            }
        }
    }
}

// ---------------- fused select+rescore (z path): one wave per row ----------------
// 64 lanes <-> 64 group-mins; row-min via shfl; ballot picks candidate groups;
// exact fp32 rescore (identical fmaf chains to the R3-passing kernel);
// lane 0 plain-stores pmin[row]. Zero atomics.
__global__ void k_rescore_row(const float* __restrict__ z, const float* __restrict__ emb,
                              const float* __restrict__ z2, const float* __restrict__ e2,
                              const float* __restrict__ m128,
                              unsigned long long* __restrict__ pmin) {
    const int t = threadIdx.x, l = t & 63;
    const int row = blockIdx.x * 4 + (t >> 6);
    const float v = m128[row * 64 + l];
    float mn = v;
    #pragma unroll
    for (int o = 1; o < 64; o <<= 1) mn = fminf(mn, __shfl_xor(mn, o));
    unsigned long long mm = __ballot(v <= mn + MARGIN);

    const float* zp = z + ((size_t)(row >> 10) << 18) + (row & 1023);
    const float z2r = z2[row];
    unsigned long long best = 0xFFFFFFFFFFFFFFFFull;
    while (mm) {
        const int g = __builtin_ctzll(mm); mm &= mm - 1;
        const int n = g * 128 + l * 2;                 // lane covers n, n+1
        const float* ep0 = emb + (size_t)n * EDIM;
        const float* ep1 = ep0 + EDIM;
        float a0l = 0.f, a0h = 0.f, a1l = 0.f, a1h = 0.f;
        #pragma unroll 4
        for (int c = 0; c < 128; ++c) {
            const float zc = zp[(size_t)c << 10];
            a0l = fmaf(zc, ep0[c], a0l);
            a1l = fmaf(zc, ep1[c], a1l);
        }
        #pragma unroll 4
        for (int c = 128; c < 256; ++c) {
            const float zc = zp[(size_t)c << 10];
            a0h = fmaf(zc, ep0[c], a0h);
            a1h = fmaf(zc, ep1[c], a1h);
        }
        // d = (z2+e2) - 2*(low+high): same arithmetic as R3 rescore
        const float d0 = fmaf(-2.f, a0l + a0h, z2r + e2[n]);
        const float d1 = fmaf(-2.f, a1l + a1h, z2r + e2[n + 1]);
        const unsigned long long p0 =
            ((unsigned long long)__float_as_uint(d0) << 32) | (unsigned)n;
        const unsigned long long p1 =
            ((unsigned long long)__float_as_uint(d1) << 32) | (unsigned)(n + 1);
        const unsigned long long pl = p0 < p1 ? p0 : p1;
        if (pl < best) best = pl;
    }
    #pragma unroll
    for (int o = 1; o < 64; o <<= 1) {
        const unsigned long long ob = __shfl_xor(best, o);
        if (ob < best) best = ob;
    }
    if (l == 0) pmin[row] = best;
}

// ---------------- fused d1 final: per column n, exact 2nd-smallest ----------------
__global__ void k_d1_final(const float* __restrict__ emb, const float* __restrict__ e2,
                           const float* __restrict__ md1, float* __restrict__ mind) {
    const int t = threadIdx.x, l = t & 63;
    const int n = blockIdx.x * 4 + (t >> 6);
    const float v = md1[n * 64 + l];
    float a1 = v, a2 = 3.4e38f;
    #pragma unroll
    for (int o = 1; o < 64; o <<= 1) {
        const float o1 = __shfl_xor(a1, o), o2 = __shfl_xor(a2, o);
        const float n1 = fminf(a1, o1);
        const float n2 = fminf(fmaxf(a1, o1), fminf(a2, o2));
        a1 = n1; a2 = n2;
    }
    const float thr = a2 + 2.0f * MARGIN_D1;   // 2x margin: covers same-group v1,v2 case
    unsigned long long mm = __ballot(v <= thr);
    const float e2n = e2[n];
    const float* np = emb + (size_t)n * EDIM;
    float b1 = 3.4e38f, b2 = 3.4e38f;
    while (mm) {
        const int g = __builtin_ctzll(mm); mm &= mm - 1;
        const int m0 = g * 128 + l * 2;               // lane covers m0, m0+1
        const float* p0 = emb + (size_t)m0 * EDIM;
        const float* p1 = p0 + EDIM;
        float c0 = 0.f, c1 = 0.f;
        #pragma unroll 8
        for (int c = 0; c < EDIM; ++c) {
            const float nc = np[c];
            c0 = fmaf(p0[c], nc, c0);
            c1 = fmaf(p1[c], nc, c1);
        }
        const float d0 = (e2[m0] + e2n) - 2.0f * c0;      // same formula as R3
        const float d1 = (e2[m0 + 1] + e2n) - 2.0f * c1;
        const float lo = fminf(d0, d1), hi = fmaxf(d0, d1);
        const float nb1 = fminf(b1, lo);
        const float nb2 = fminf(fmaxf(b1, lo), fminf(b2, hi));
        b1 = nb1; b2 = nb2;
    }
    #pragma unroll
    for (int o = 1; o < 64; o <<= 1) {
        const float o1 = __shfl_xor(b1, o), o2 = __shfl_xor(b2, o);
        const float n1 = fminf(b1, o1);
        const float n2 = fminf(fmaxf(b1, o1), fminf(b2, o2));
        b1 = n1; b2 = n2;
    }
    if (l == 0) mind[n] = b2;
}

// ---------------- unpack packed min -> idx / dmin / indices output ----------------
__global__ void k_unpack(const unsigned long long* __restrict__ pmin,
                         int* __restrict__ idxi, float* __restrict__ dmin,
                         float* __restrict__ out_idx) {
    int i = blockIdx.x * 256 + threadIdx.x;
    unsigned long long p = pmin[i];
    int idx  = (int)(p & 0xFFFFFFFFull);
    idxi[i]  = idx;
    dmin[i]  = __uint_as_float((unsigned)(p >> 32));
    out_idx[i] = (float)idx;
}

// ---------------- gather + straight-through + MSE accumulation ----------------
__global__ void k_epilogue(const float* __restrict__ z, const float* __restrict__ emb,
                           const int* __restrict__ idxi,
                           float* __restrict__ out_zq, float* __restrict__ out_zfl,
                           double* __restrict__ mse) {
    const int j4 = blockIdx.x * 256 + threadIdx.x;   // float4 index into bchw
    const int j  = j4 * 4;
    const int b  = j >> 18;
    const int c  = (j >> 10) & 255;
    const int hw = j & 1023;
    const int ib = (b << 10) + hw;
    const float4 zv = *reinterpret_cast<const float4*>(z + j);
    const float q0 = emb[(size_t)idxi[ib + 0] * EDIM + c];
    const float q1 = emb[(size_t)idxi[ib + 1] * EDIM + c];
    const float q2 = emb[(size_t)idxi[ib + 2] * EDIM + c];
    const float q3 = emb[(size_t)idxi[ib + 3] * EDIM + c];
    const float d0 = q0 - zv.x, d1 = q1 - zv.y, d2 = q2 - zv.z, d3 = q3 - zv.w;
    const float4 st = {zv.x + d0, zv.y + d1, zv.z + d2, zv.w + d3};  // z + (q-z)
    *reinterpret_cast<float4*>(out_zq + j) = st;
    out_zfl[j + 0] = st.x; out_zfl[j + 1] = st.y; out_zfl[j + 2] = st.z; out_zfl[j + 3] = st.w;

    double s = (double)(d0 * d0) + (double)(d1 * d1) + (double)(d2 * d2) + (double)(d3 * d3);
    #pragma unroll
    for (int m = 32; m; m >>= 1) s += __shfl_down(s, m);
    __shared__ double part[4];
    if ((threadIdx.x & 63) == 0) part[threadIdx.x >> 6] = s;
    __syncthreads();
    if (threadIdx.x == 0) atomicAdd(mse, part[0] + part[1] + part[2] + part[3]);
}

// ---------------- distances output [b,w] ----------------
__global__ void k_distances(const float* __restrict__ dmin, float* __restrict__ out_d) {
    int t = threadIdx.x;            // 512 threads
    int b = t >> 5, w = t & 31;
    float s = 0.f;
    #pragma unroll
    for (int h = 0; h < HH; ++h) {
        float d = dmin[(b << 10) + (h << 5) + w];
        s += d * d;
    }
    float mean = s * (1.0f / 32.0f);
    out_d[t] = expf(-mean / 0.02f);
}

// ---------------- finalize: tmd, cbvar, loss ----------------
__global__ void k_finalize(const float* __restrict__ mind, const double* __restrict__ mse,
                           float* __restrict__ out) {
    const int t = threadIdx.x;      // 256 threads, 1 block
    double s = 0.0, ss = 0.0;
    for (int n = t; n < N_E; n += 256) {
        const double v = (double)mind[n];
        s += v; ss += v * v;
    }
    #pragma unroll
    for (int m = 32; m; m >>= 1) { s += __shfl_down(s, m); ss += __shfl_down(ss, m); }
    __shared__ double rs[4], rss[4];
    if ((t & 63) == 0) { rs[t >> 6] = s; rss[t >> 6] = ss; }
    __syncthreads();
    if (t == 0) {
        const double S  = rs[0] + rs[1] + rs[2] + rs[3];
        const double SS = rss[0] + rss[1] + rss[2] + rss[3];
        const float tmd = (float)S;
        double var = (SS - S * S / (double)N_E) / (double)(N_E - 1);
        if (var < 0.0) var = 0.0;
        const float cbv = (float)sqrt(var);
        const float m1  = (float)(*mse / (double)NELEM);
        const float lossf = m1 + 0.25f * m1 - tmd;
        out[O_LOSS] = lossf;
        out[O_CBV]  = cbv;
        out[O_TMD]  = tmd;
    }
}

extern "C" void kernel_launch(void* const* d_in, const int* in_sizes, int n_in,
                              void* d_out, int out_size, void* d_ws, size_t ws_size,
                              hipStream_t stream) {
    const float* z   = (const float*)d_in[0];
    const float* emb = (const float*)d_in[1];
    float* out = (float*)d_out;
    char*  ws  = (char*)d_ws;

    unsigned long long* pmin = (unsigned long long*)(ws + WS_PMIN);
    int*      idxi  = (int*)    (ws + WS_IDX);
    float*    dmin  = (float*)  (ws + WS_DMIN);
    float*    e2    = (float*)  (ws + WS_E2);
    float*    z2    = (float*)  (ws + WS_Z2);
    double*   mse   = (double*) (ws + WS_MSE);
    float*    mind  = (float*)  (ws + WS_MIND);
    bf16x8*   zA    = (bf16x8*) (ws + WS_ZA);
    bf16x8*   eB    = (bf16x8*) (ws + WS_EB);
    float*    m128  = (float*)  (ws + WS_M128);
    float*    md1   = (float*)  (ws + WS_MD1);

    k_init       <<<1,    64,  0, stream>>>(mse);
    k_e2         <<<2048, 256, 0, stream>>>(emb, e2);
    k_z2         <<<64,   256, 0, stream>>>(z, z2);
    k_convert_z  <<<dim3(16, 4, 16), 256, 0, stream>>>(z, zA);
    k_convert_e  <<<1024, 256, 0, stream>>>(emb, eB);
    k_cand       <<<dim3(128, 8), 256, 0, stream>>>(zA, eB, e2, m128);
    k_rescore_row<<<4096, 256, 0, stream>>>(z, emb, z2, e2, m128, pmin);
    k_cand_d1    <<<dim3(64, 8), 256, 0, stream>>>(eB, e2, md1);
    k_d1_final   <<<2048, 256, 0, stream>>>(emb, e2, md1, mind);
    k_unpack     <<<64,   256, 0, stream>>>(pmin, idxi, dmin, out + O_IDX);
    k_epilogue   <<<4096, 256, 0, stream>>>(z, emb, idxi, out + O_ZQ, out + O_ZFL, mse);
    k_distances  <<<1,    512, 0, stream>>>(dmin, out + O_DIST);
    k_finalize   <<<1,    256, 0, stream>>>(mind, mse, out);
}

// Round 5
// 1279.298 us; speedup vs baseline: 1.6844x; 1.6844x over previous
//
#include <hip/hip_runtime.h>
#include <stdint.h>

// ---------------- problem constants ----------------
#define N_E   8192
#define EDIM  256
#define NB    16
#define HH    32
#define WW    32
#define HW    1024            // H*W
#define NI    16384           // NB*HW (rows of zf)
#define NELEM 4194304         // NB*EDIM*HW

#define MARGIN_D1 1e-9f       // d1 rescore margin (split-MFMA err ~1e-11)

// output flat offsets (reference return order)
#define O_ZQ   0
#define O_LOSS 4194304
#define O_DIST 4194305
#define O_IDX  4194817
#define O_ZFL  4211201
#define O_CBV  8405505
#define O_TMD  8405506

// workspace byte offsets (~28 MB)
#define WS_IDX   0x0        // i32 * 16384
#define WS_DMIN  0x20000    // f32 * 16384
#define WS_E2    0x40000    // f32 * 8192
#define WS_Z2    0x50000    // f32 * 16384
#define WS_MSE   0x60000    // double
#define WS_MIND  0x61000    // f32 * 8192
#define WS_PZ    0x70000    // u64 * 16384*8*2  (2 MB)
#define WS_PD1   0x270000   // u64 * 8192*8*2   (1 MB)
#define WS_ZAH   0x400000   // bf16 * 16384*256 fragment-major (8 MB)
#define WS_ZAL   0xC00000   // bf16 low-residual (8 MB)
#define WS_EBH   0x1400000  // bf16 * 8192*256 fragment-major (4 MB)
#define WS_EBL   0x1800000  // bf16 low-residual (4 MB)

typedef __attribute__((ext_vector_type(8))) short bf16x8;
typedef __attribute__((ext_vector_type(4))) float f32x4;

__device__ __forceinline__ short f2bf(float f) {   // round-to-nearest-even
    unsigned u = __float_as_uint(f);
    u += 0x7fffu + ((u >> 16) & 1u);
    return (short)(u >> 16);
}
__device__ __forceinline__ float bf2f(short h) {
    return __uint_as_float(((unsigned)(unsigned short)h) << 16);
}
// monotone float->u32 key (handles negatives)
__device__ __forceinline__ unsigned keyf(float f) {
    unsigned b = __float_as_uint(f);
    return (b & 0x80000000u) ? ~b : (b | 0x80000000u);
}
__device__ __forceinline__ float unkeyf(unsigned k) {
    return (k & 0x80000000u) ? __uint_as_float(k ^ 0x80000000u) : __uint_as_float(~k);
}
// running two-smallest insert / merge on packed u64
__device__ __forceinline__ void ins2(unsigned long long& a1, unsigned long long& a2,
                                     unsigned long long v) {
    if (v < a1) { a2 = a1; a1 = v; } else if (v < a2) { a2 = v; }
}
__device__ __forceinline__ void mrg2(unsigned long long& a1, unsigned long long& a2,
                                     unsigned long long b1, unsigned long long b2) {
    unsigned long long n1 = a1 < b1 ? a1 : b1;
    unsigned long long mx = a1 < b1 ? b1 : a1;
    unsigned long long mn = a2 < b2 ? a2 : b2;
    a1 = n1; a2 = mx < mn ? mx : mn;
}

// ---------------- init ----------------
__global__ void k_init(double* __restrict__ mse) {
    if (threadIdx.x == 0) *mse = 0.0;
}

// ---------------- e2[n] = sum_c emb[n,c]^2 ----------------
__global__ void k_e2(const float* __restrict__ emb, float* __restrict__ e2) {
    int row  = blockIdx.x * 4 + (threadIdx.x >> 6);
    int lane = threadIdx.x & 63;
    float4 v = *reinterpret_cast<const float4*>(emb + (size_t)row * EDIM + lane * 4);
    float s = v.x * v.x + v.y * v.y + v.z * v.z + v.w * v.w;
    #pragma unroll
    for (int m = 32; m; m >>= 1) s += __shfl_xor(s, m);
    if (lane == 0) e2[row] = s;
}

// ---------------- z2[i] = sum_c z[b,c,h,w]^2 ----------------
__global__ void k_z2(const float* __restrict__ z, float* __restrict__ z2) {
    int i = blockIdx.x * 256 + threadIdx.x;
    int b = i >> 10, hw = i & 1023;
    const float* p = z + (size_t)b * EDIM * HW + hw;
    float s = 0.f;
    #pragma unroll 8
    for (int c = 0; c < EDIM; ++c) { float v = p[(size_t)c * HW]; s += v * v; }
    z2[i] = s;
}

// ---------------- z -> split bf16 fragment-major (hi + residual) ----------------
__global__ void k_convert_z(const float* __restrict__ z,
                            bf16x8* __restrict__ zAh, bf16x8* __restrict__ zAl) {
    __shared__ float lds[64][65];
    const int t   = threadIdx.x;
    const int hw0 = blockIdx.x * 64;
    const int c0  = blockIdx.y * 64;
    const int b   = blockIdx.z;
    #pragma unroll
    for (int cc = 0; cc < 4; ++cc) {
        const int cl = cc * 16 + (t >> 4);
        const float4 v = *reinterpret_cast<const float4*>(
            z + ((size_t)(b * 256 + c0 + cl) << 10) + hw0 + (t & 15) * 4);
        lds[cl][(t & 15) * 4 + 0] = v.x; lds[cl][(t & 15) * 4 + 1] = v.y;
        lds[cl][(t & 15) * 4 + 2] = v.z; lds[cl][(t & 15) * 4 + 3] = v.w;
    }
    __syncthreads();
    const int hl = t & 63;
    const int i  = b * 1024 + hw0 + hl;
    const int ig = i >> 4, r = i & 15;
    #pragma unroll
    for (int half = 0; half < 2; ++half) {
        const int kqi = (t >> 6) + half * 4;
        const int kq  = (c0 >> 3) + kqi;
        bf16x8 oh, ol;
        #pragma unroll
        for (int j = 0; j < 8; ++j) {
            const float f = lds[kqi * 8 + j][hl];
            const short h = f2bf(f);
            oh[j] = h;
            ol[j] = f2bf(f - bf2f(h));
        }
        zAh[(ig * 32 + kq) * 16 + r] = oh;
        zAl[(ig * 32 + kq) * 16 + r] = ol;
    }
}

// ---------------- emb -> split bf16 fragment-major ----------------
__global__ void k_convert_e(const float* __restrict__ emb,
                            bf16x8* __restrict__ eBh, bf16x8* __restrict__ eBl) {
    const int t  = threadIdx.x;
    const int kq = t & 31;
    const int n  = blockIdx.x * 8 + (t >> 5);
    const float4 u = *reinterpret_cast<const float4*>(emb + (size_t)n * EDIM + kq * 8);
    const float4 v = *reinterpret_cast<const float4*>(emb + (size_t)n * EDIM + kq * 8 + 4);
    const float fv[8] = {u.x, u.y, u.z, u.w, v.x, v.y, v.z, v.w};
    bf16x8 oh, ol;
    #pragma unroll
    for (int j = 0; j < 8; ++j) {
        const short h = f2bf(fv[j]);
        oh[j] = h;
        ol[j] = f2bf(fv[j] - bf2f(h));
    }
    eBh[((n >> 4) * 32 + kq) * 16 + (n & 15)] = oh;
    eBl[((n >> 4) * 32 + kq) * 16 + (n & 15)] = ol;
}

// ---------------- split-MFMA candidate pass (z path) ----------------
// S' = zh.eh + zh.el + zl.eh (err ~1e-9); d' = fmaf(-2,S', z2+e2) in the
// reference's quantized fp32 domain; per-(row,chunk) top-2 packed (d',n).
__launch_bounds__(256, 2)
__global__ void k_cand(const bf16x8* __restrict__ zAh, const bf16x8* __restrict__ zAl,
                       const bf16x8* __restrict__ eBh, const bf16x8* __restrict__ eBl,
                       const float* __restrict__ z2, const float* __restrict__ e2,
                       unsigned long long* __restrict__ pz) {
    const int t = threadIdx.x;
    const int w = t >> 6, l = t & 63;
    const int lo16 = l & 15, hi4 = l >> 4;
    const int iblk = blockIdx.x, chunk = blockIdx.y;
    const int ig0 = (iblk * 128 + w * 32) >> 4;

    float z2r[2][4];
    #pragma unroll
    for (int ig = 0; ig < 2; ++ig)
        #pragma unroll
        for (int reg = 0; reg < 4; ++reg)
            z2r[ig][reg] = z2[iblk * 128 + w * 32 + ig * 16 + hi4 * 4 + reg];

    unsigned long long t1[2][4], t2[2][4];
    #pragma unroll
    for (int ig = 0; ig < 2; ++ig)
        #pragma unroll
        for (int reg = 0; reg < 4; ++reg) { t1[ig][reg] = ~0ull; t2[ig][reg] = ~0ull; }

    for (int ns = 0; ns < 8; ++ns) {
        const int n0 = chunk * 1024 + ns * 128;
        f32x4 acc[2][8];
        #pragma unroll
        for (int ig = 0; ig < 2; ++ig)
            #pragma unroll
            for (int cg = 0; cg < 8; ++cg) acc[ig][cg] = (f32x4){0.f, 0.f, 0.f, 0.f};

        #pragma unroll
        for (int st = 0; st < 8; ++st) {
            const bf16x8 ah0 = zAh[((ig0 + 0) * 32 + st * 4 + hi4) * 16 + lo16];
            const bf16x8 ah1 = zAh[((ig0 + 1) * 32 + st * 4 + hi4) * 16 + lo16];
            const bf16x8 al0 = zAl[((ig0 + 0) * 32 + st * 4 + hi4) * 16 + lo16];
            const bf16x8 al1 = zAl[((ig0 + 1) * 32 + st * 4 + hi4) * 16 + lo16];
            #pragma unroll
            for (int cg = 0; cg < 8; ++cg) {
                const bf16x8 bh = eBh[(((n0 >> 4) + cg) * 32 + st * 4 + hi4) * 16 + lo16];
                const bf16x8 bl = eBl[(((n0 >> 4) + cg) * 32 + st * 4 + hi4) * 16 + lo16];
                acc[0][cg] = __builtin_amdgcn_mfma_f32_16x16x32_bf16(ah0, bh, acc[0][cg], 0, 0, 0);
                acc[0][cg] = __builtin_amdgcn_mfma_f32_16x16x32_bf16(ah0, bl, acc[0][cg], 0, 0, 0);
                acc[0][cg] = __builtin_amdgcn_mfma_f32_16x16x32_bf16(al0, bh, acc[0][cg], 0, 0, 0);
                acc[1][cg] = __builtin_amdgcn_mfma_f32_16x16x32_bf16(ah1, bh, acc[1][cg], 0, 0, 0);
                acc[1][cg] = __builtin_amdgcn_mfma_f32_16x16x32_bf16(ah1, bl, acc[1][cg], 0, 0, 0);
                acc[1][cg] = __builtin_amdgcn_mfma_f32_16x16x32_bf16(al1, bh, acc[1][cg], 0, 0, 0);
            }
        }
        float e2v[8];
        #pragma unroll
        for (int cg = 0; cg < 8; ++cg) e2v[cg] = e2[n0 + cg * 16 + lo16];
        // C/D: col=lane&15, row=(lane>>4)*4+reg [m89]
        #pragma unroll
        for (int ig = 0; ig < 2; ++ig) {
            #pragma unroll
            for (int reg = 0; reg < 4; ++reg) {
                #pragma unroll
                for (int cg = 0; cg < 8; ++cg) {
                    const float d = fmaf(-2.f, acc[ig][cg][reg], z2r[ig][reg] + e2v[cg]);
                    const unsigned long long pk =
                        ((unsigned long long)keyf(d) << 32) | (unsigned)(n0 + cg * 16 + lo16);
                    ins2(t1[ig][reg], t2[ig][reg], pk);
                }
            }
        }
    }
    // merge across the 16 column-lanes (hi4 groups stay separate)
    #pragma unroll
    for (int ig = 0; ig < 2; ++ig) {
        #pragma unroll
        for (int reg = 0; reg < 4; ++reg) {
            unsigned long long a1 = t1[ig][reg], a2 = t2[ig][reg];
            #pragma unroll
            for (int o = 1; o < 16; o <<= 1) {
                const unsigned long long b1 = __shfl_xor(a1, o);
                const unsigned long long b2 = __shfl_xor(a2, o);
                mrg2(a1, a2, b1, b2);
            }
            if (lo16 == 0) {
                const int row = iblk * 128 + w * 32 + ig * 16 + hi4 * 4 + reg;
                pz[(row * 8 + chunk) * 2 + 0] = a1;
                pz[(row * 8 + chunk) * 2 + 1] = a2;
            }
        }
    }
}

// ---------------- split-MFMA candidate pass (d1): both operands = emb ----------
// key on q = e2[m] - 2 S (e2[n] is row-constant); values-only -> ties harmless
__launch_bounds__(256, 2)
__global__ void k_cand_d1(const bf16x8* __restrict__ eBh, const bf16x8* __restrict__ eBl,
                          const float* __restrict__ e2,
                          unsigned long long* __restrict__ pd1) {
    const int t = threadIdx.x;
    const int w = t >> 6, l = t & 63;
    const int lo16 = l & 15, hi4 = l >> 4;
    const int iblk = blockIdx.x, chunk = blockIdx.y;
    const int ig0 = (iblk * 128 + w * 32) >> 4;

    unsigned long long t1[2][4], t2[2][4];
    #pragma unroll
    for (int ig = 0; ig < 2; ++ig)
        #pragma unroll
        for (int reg = 0; reg < 4; ++reg) { t1[ig][reg] = ~0ull; t2[ig][reg] = ~0ull; }

    for (int ns = 0; ns < 8; ++ns) {
        const int n0 = chunk * 1024 + ns * 128;   // m-range
        f32x4 acc[2][8];
        #pragma unroll
        for (int ig = 0; ig < 2; ++ig)
            #pragma unroll
            for (int cg = 0; cg < 8; ++cg) acc[ig][cg] = (f32x4){0.f, 0.f, 0.f, 0.f};

        #pragma unroll
        for (int st = 0; st < 8; ++st) {
            const bf16x8 ah0 = eBh[((ig0 + 0) * 32 + st * 4 + hi4) * 16 + lo16];
            const bf16x8 ah1 = eBh[((ig0 + 1) * 32 + st * 4 + hi4) * 16 + lo16];
            const bf16x8 al0 = eBl[((ig0 + 0) * 32 + st * 4 + hi4) * 16 + lo16];
            const bf16x8 al1 = eBl[((ig0 + 1) * 32 + st * 4 + hi4) * 16 + lo16];
            #pragma unroll
            for (int cg = 0; cg < 8; ++cg) {
                const bf16x8 bh = eBh[(((n0 >> 4) + cg) * 32 + st * 4 + hi4) * 16 + lo16];
                const bf16x8 bl = eBl[(((n0 >> 4) + cg) * 32 + st * 4 + hi4) * 16 + lo16];
                acc[0][cg] = __builtin_amdgcn_mfma_f32_16x16x32_bf16(ah0, bh, acc[0][cg], 0, 0, 0);
                acc[0][cg] = __builtin_amdgcn_mfma_f32_16x16x32_bf16(ah0, bl, acc[0][cg], 0, 0, 0);
                acc[0][cg] = __builtin_amdgcn_mfma_f32_16x16x32_bf16(al0, bh, acc[0][cg], 0, 0, 0);
                acc[1][cg] = __builtin_amdgcn_mfma_f32_16x16x32_bf16(ah1, bh, acc[1][cg], 0, 0, 0);
                acc[1][cg] = __builtin_amdgcn_mfma_f32_16x16x32_bf16(ah1, bl, acc[1][cg], 0, 0, 0);
                acc[1][cg] = __builtin_amdgcn_mfma_f32_16x16x32_bf16(al1, bh, acc[1][cg], 0, 0, 0);
            }
        }
        float e2v[8];
        #pragma unroll
        for (int cg = 0; cg < 8; ++cg) e2v[cg] = e2[n0 + cg * 16 + lo16];
        #pragma unroll
        for (int ig = 0; ig < 2; ++ig) {
            #pragma unroll
            for (int reg = 0; reg < 4; ++reg) {
                #pragma unroll
                for (int cg = 0; cg < 8; ++cg) {
                    const float q = fmaf(-2.f, acc[ig][cg][reg], e2v[cg]);
                    const unsigned long long pk =
                        ((unsigned long long)keyf(q) << 32) | (unsigned)(n0 + cg * 16 + lo16);
                    ins2(t1[ig][reg], t2[ig][reg], pk);
                }
            }
        }
    }
    #pragma unroll
    for (int ig = 0; ig < 2; ++ig) {
        #pragma unroll
        for (int reg = 0; reg < 4; ++reg) {
            unsigned long long a1 = t1[ig][reg], a2 = t2[ig][reg];
            #pragma unroll
            for (int o = 1; o < 16; o <<= 1) {
                const unsigned long long b1 = __shfl_xor(a1, o);
                const unsigned long long b2 = __shfl_xor(a2, o);
                mrg2(a1, a2, b1, b2);
            }
            if (lo16 == 0) {
                const int row = iblk * 128 + w * 32 + ig * 16 + hi4 * 4 + reg;  // = n
                pd1[(row * 8 + chunk) * 2 + 0] = a1;
                pd1[(row * 8 + chunk) * 2 + 1] = a2;
            }
        }
    }
}

// ---------------- z merge: global top-2 + exact fp32 rescore + write ----------------
// lane = (row_local<<2) | (code_slot<<1) | half ; 16 rows per wave
__global__ void k_zmerge(const float* __restrict__ z, const float* __restrict__ emb,
                         const float* __restrict__ z2, const float* __restrict__ e2,
                         const unsigned long long* __restrict__ pz,
                         int* __restrict__ idxi, float* __restrict__ dmin,
                         float* __restrict__ out_idx) {
    const int t = threadIdx.x, l = t & 63;
    const int row = blockIdx.x * 64 + (t >> 6) * 16 + (l >> 2);
    const int cs = (l >> 1) & 1, hf = l & 1;
    // 4 lanes/row each read 4 of the row's 16 candidates
    unsigned long long a1 = ~0ull, a2 = ~0ull;
    #pragma unroll
    for (int k = 0; k < 4; ++k)
        ins2(a1, a2, pz[row * 16 + (l & 3) * 4 + k]);
    #pragma unroll
    for (int o = 1; o < 4; o <<= 1) {
        const unsigned long long b1 = __shfl_xor(a1, o);
        const unsigned long long b2 = __shfl_xor(a2, o);
        mrg2(a1, a2, b1, b2);
    }
    const int n = (unsigned)(cs ? a2 : a1);
    // exact rescore: two 128-chains (R3-validated), halves combined via shfl
    const float* zp = z + ((size_t)(row >> 10) << 18) + (row & 1023);
    const float* ep = emb + (size_t)n * EDIM;
    float acc = 0.f;
    #pragma unroll 8
    for (int c = 0; c < 128; ++c) {
        const int cc = hf * 128 + c;
        acc = fmaf(zp[(size_t)cc << 10], ep[cc], acc);
    }
    const float total = acc + __shfl_xor(acc, 1);
    const float d = fmaf(-2.f, total, z2[row] + e2[n]);
    unsigned long long pk = ((unsigned long long)__float_as_uint(d) << 32) | (unsigned)n;
    const unsigned long long op = __shfl_xor(pk, 2);
    if (op < pk) pk = op;
    if ((l & 3) == 0) {
        const int ni = (int)(pk & 0xFFFFFFFFull);
        idxi[row] = ni;
        dmin[row] = __uint_as_float((unsigned)(pk >> 32));
        out_idx[row] = (float)ni;
    }
}

// ---------------- d1 merge: per column, exact 2nd-smallest ----------------
__global__ void k_d1merge(const float* __restrict__ emb, const float* __restrict__ e2,
                          const unsigned long long* __restrict__ pd1,
                          float* __restrict__ mind) {
    const int n = blockIdx.x * 256 + threadIdx.x;
    unsigned long long w1 = ~0ull, w2 = ~0ull;
    unsigned long long ent[16];
    #pragma unroll
    for (int e = 0; e < 16; ++e) { ent[e] = pd1[n * 16 + e]; ins2(w1, w2, ent[e]); }
    const float thr = unkeyf((unsigned)(w2 >> 32)) + MARGIN_D1;
    const float e2n = e2[n];
    const float* np = emb + (size_t)n * EDIM;
    float b1 = 3.4e38f, b2 = 3.4e38f;
    #pragma unroll 1
    for (int e = 0; e < 16; ++e) {
        const float af = unkeyf((unsigned)(ent[e] >> 32));
        if (af > thr) continue;
        const int m = (unsigned)ent[e];
        const float* ep = emb + (size_t)m * EDIM;
        float acc = 0.f;
        #pragma unroll 8
        for (int c = 0; c < EDIM; ++c) acc = fmaf(ep[c], np[c], acc);   // R3 chain
        const float dv = (e2[m] + e2n) - 2.0f * acc;
        if (dv < b1) { b2 = b1; b1 = dv; } else if (dv < b2) { b2 = dv; }
    }
    mind[n] = b2;
}

// ---------------- gather + straight-through + MSE ----------------
__global__ void k_epilogue(const float* __restrict__ z, const float* __restrict__ emb,
                           const int* __restrict__ idxi,
                           float* __restrict__ out_zq, float* __restrict__ out_zfl,
                           double* __restrict__ mse) {
    const int j4 = blockIdx.x * 256 + threadIdx.x;
    const int j  = j4 * 4;
    const int b  = j >> 18;
    const int c  = (j >> 10) & 255;
    const int hw = j & 1023;
    const int ib = (b << 10) + hw;
    const float4 zv = *reinterpret_cast<const float4*>(z + j);
    const float q0 = emb[(size_t)idxi[ib + 0] * EDIM + c];
    const float q1 = emb[(size_t)idxi[ib + 1] * EDIM + c];
    const float q2 = emb[(size_t)idxi[ib + 2] * EDIM + c];
    const float q3 = emb[(size_t)idxi[ib + 3] * EDIM + c];
    const float d0 = q0 - zv.x, d1 = q1 - zv.y, d2 = q2 - zv.z, d3 = q3 - zv.w;
    const float4 st = {zv.x + d0, zv.y + d1, zv.z + d2, zv.w + d3};  // z + (q-z)
    *reinterpret_cast<float4*>(out_zq + j) = st;
    out_zfl[j + 0] = st.x; out_zfl[j + 1] = st.y; out_zfl[j + 2] = st.z; out_zfl[j + 3] = st.w;

    double s = (double)(d0 * d0) + (double)(d1 * d1) + (double)(d2 * d2) + (double)(d3 * d3);
    #pragma unroll
    for (int m = 32; m; m >>= 1) s += __shfl_down(s, m);
    __shared__ double part[4];
    if ((threadIdx.x & 63) == 0) part[threadIdx.x >> 6] = s;
    __syncthreads();
    if (threadIdx.x == 0) atomicAdd(mse, part[0] + part[1] + part[2] + part[3]);
}

// ---------------- distances output [b,w] ----------------
__global__ void k_distances(const float* __restrict__ dmin, float* __restrict__ out_d) {
    int t = threadIdx.x;            // 512 threads
    int b = t >> 5, w = t & 31;
    float s = 0.f;
    #pragma unroll
    for (int h = 0; h < HH; ++h) {
        float d = dmin[(b << 10) + (h << 5) + w];
        s += d * d;
    }
    float mean = s * (1.0f / 32.0f);
    out_d[t] = expf(-mean / 0.02f);
}

// ---------------- finalize: tmd, cbvar, loss ----------------
__global__ void k_finalize(const float* __restrict__ mind, const double* __restrict__ mse,
                           float* __restrict__ out) {
    const int t = threadIdx.x;      // 256 threads, 1 block
    double s = 0.0, ss = 0.0;
    for (int n = t; n < N_E; n += 256) {
        const double v = (double)mind[n];
        s += v; ss += v * v;
    }
    #pragma unroll
    for (int m = 32; m; m >>= 1) { s += __shfl_down(s, m); ss += __shfl_down(ss, m); }
    __shared__ double rs[4], rss[4];
    if ((t & 63) == 0) { rs[t >> 6] = s; rss[t >> 6] = ss; }
    __syncthreads();
    if (t == 0) {
        const double S  = rs[0] + rs[1] + rs[2] + rs[3];
        const double SS = rss[0] + rss[1] + rss[2] + rss[3];
        const float tmd = (float)S;
        double var = (SS - S * S / (double)N_E) / (double)(N_E - 1);
        if (var < 0.0) var = 0.0;
        const float cbv = (float)sqrt(var);
        const float m1  = (float)(*mse / (double)NELEM);
        const float lossf = m1 + 0.25f * m1 - tmd;
        out[O_LOSS] = lossf;
        out[O_CBV]  = cbv;
        out[O_TMD]  = tmd;
    }
}

extern "C" void kernel_launch(void* const* d_in, const int* in_sizes, int n_in,
                              void* d_out, int out_size, void* d_ws, size_t ws_size,
                              hipStream_t stream) {
    const float* z   = (const float*)d_in[0];
    const float* emb = (const float*)d_in[1];
    float* out = (float*)d_out;
    char*  ws  = (char*)d_ws;

    int*      idxi = (int*)    (ws + WS_IDX);
    float*    dmin = (float*)  (ws + WS_DMIN);
    float*    e2   = (float*)  (ws + WS_E2);
    float*    z2   = (float*)  (ws + WS_Z2);
    double*   mse  = (double*) (ws + WS_MSE);
    float*    mind = (float*)  (ws + WS_MIND);
    unsigned long long* pz  = (unsigned long long*)(ws + WS_PZ);
    unsigned long long* pd1 = (unsigned long long*)(ws + WS_PD1);
    bf16x8*   zAh  = (bf16x8*) (ws + WS_ZAH);
    bf16x8*   zAl  = (bf16x8*) (ws + WS_ZAL);
    bf16x8*   eBh  = (bf16x8*) (ws + WS_EBH);
    bf16x8*   eBl  = (bf16x8*) (ws + WS_EBL);

    k_init     <<<1,    64,  0, stream>>>(mse);
    k_e2       <<<2048, 256, 0, stream>>>(emb, e2);
    k_z2       <<<64,   256, 0, stream>>>(z, z2);
    k_convert_z<<<dim3(16, 4, 16), 256, 0, stream>>>(z, zAh, zAl);
    k_convert_e<<<1024, 256, 0, stream>>>(emb, eBh, eBl);
    k_cand     <<<dim3(128, 8), 256, 0, stream>>>(zAh, zAl, eBh, eBl, z2, e2, pz);
    k_cand_d1  <<<dim3(64, 8),  256, 0, stream>>>(eBh, eBl, e2, pd1);
    k_zmerge   <<<256,  256, 0, stream>>>(z, emb, z2, e2, pz, idxi, dmin, out + O_IDX);
    k_d1merge  <<<32,   256, 0, stream>>>(emb, e2, pd1, mind);
    k_epilogue <<<4096, 256, 0, stream>>>(z, emb, idxi, out + O_ZQ, out + O_ZFL, mse);
    k_distances<<<1,    512, 0, stream>>>(dmin, out + O_DIST);
    k_finalize <<<1,    256, 0, stream>>>(mind, mse, out);
}